// Round 2
// baseline (1283.322 us; speedup 1.0000x reference)
//
#include <hip/hip_runtime.h>
#include <hip/hip_bf16.h>
#include <math.h>

typedef __attribute__((ext_vector_type(8))) short bf16x8;     // 8 bf16 = 4 VGPRs
typedef __attribute__((ext_vector_type(4))) float f32x4;      // MFMA accumulator
typedef __attribute__((ext_vector_type(8))) unsigned short u16x8;

typedef const float* fptr;

__device__ inline float b2f(unsigned short u) {
    union { unsigned int i; float f; } v; v.i = ((unsigned int)u) << 16; return v.f;
}
__device__ inline unsigned short f2b(float x) {
    __hip_bfloat16 h = __float2bfloat16(x);
    return *(unsigned short*)&h;
}
#define BF2F(x) __bfloat162float(x)
__device__ inline float elu_f(float x) { return x > 0.f ? x : expm1f(x); }

// ---------------------------------------------------------------------------
// Kernel 1: small in_proj (query->q, value1->v1), fp32 in, fp32 out (ws)
// grid (8 groups, 16 rows, 2 matrices), block 256.
// Each block: one (row, 128-col group): y = x@W[:,g] + b, elu, groupnorm.
// ---------------------------------------------------------------------------
__global__ __launch_bounds__(256) void small_proj(
    fptr x0, fptr W0, fptr b0, fptr g0, fptr be0,
    fptr x1, fptr W1, fptr b1, fptr g1, fptr be1,
    float* out0, float* out1)
{
    __shared__ float xs[1024];
    __shared__ float part[2][128];
    __shared__ float r4[4][2];
    int hgrp = blockIdx.x;     // 0..7 group
    int row  = blockIdx.y;     // 0..15
    int which = blockIdx.z;
    fptr x  = which ? x1  : x0;
    fptr W  = which ? W1  : W0;
    fptr bi = which ? b1  : b0;
    fptr g  = which ? g1  : g0;
    fptr be = which ? be1 : be0;
    float* outp = which ? out1 : out0;
    int t = threadIdx.x, lane = t & 63, wv = t >> 6;
    for (int i = t; i < 1024; i += 256) xs[i] = x[row * 1024 + i];
    __syncthreads();
    int cl = t & 127, kh = t >> 7;
    int col = hgrp * 128 + cl;
    float acc = 0.f;
    const float* wp = W + (size_t)(kh * 512) * 1024 + col;
    for (int k = 0; k < 512; k++) acc += xs[kh * 512 + k] * wp[(size_t)k * 1024];
    part[kh][cl] = acc;
    __syncthreads();
    float e = 0.f;
    if (t < 128) e = elu_f(part[0][t] + part[1][t] + bi[col]);
    float s = e, ss = e * e;
    for (int m = 32; m > 0; m >>= 1) { s += __shfl_xor(s, m); ss += __shfl_xor(ss, m); }
    if (lane == 0) { r4[wv][0] = s; r4[wv][1] = ss; }
    __syncthreads();
    float S  = r4[0][0] + r4[1][0] + r4[2][0] + r4[3][0];
    float SS = r4[0][1] + r4[1][1] + r4[2][1] + r4[3][1];
    float mean = S * (1.f / 128.f);
    float var  = SS * (1.f / 128.f) - mean * mean;
    float inv  = rsqrtf(var + 1e-3f);
    if (t < 128) outp[row * 1024 + col] = (e - mean) * inv * g[col] + be[col];
}

// ---------------------------------------------------------------------------
// Kernel 2: big in_proj via bf16 MFMA. fp32 inputs converted in staging.
// z = groupnorm(elu(A @ W + b)) stored bf16.
// Tile 128x128, BK=32, block 256 (4 waves: wave w -> rows (w&1)*64, cols (w>>1)*64).
// mfma_f32_16x16x32_bf16: A/B frag idx16=lane&15, k=(lane>>4)*8+j; C/D col=lane&15,
// row=(lane>>4)*4+reg.   Epilogue: elu + per-row groupnorm (128-col tile == one group).
// ---------------------------------------------------------------------------
__global__ __launch_bounds__(256) void mfma_gemm(
    fptr A0, fptr W0, fptr b0, fptr g0, fptr be0,
    fptr A1, fptr W1, fptr b1, fptr g1, fptr be1,
    __hip_bfloat16* Z0, __hip_bfloat16* Z1)
{
    __shared__ unsigned short As[128][48];   // [row][k], 96B rows (16B-aligned)
    __shared__ unsigned short Bs[128][48];   // [col][k] (W staged transposed)
    __shared__ float sstat[128][2][2];       // [row][colhalf][sum/sumsq]
    int zi = blockIdx.z;
    fptr A    = zi ? A1 : A0;
    fptr W    = zi ? W1 : W0;
    fptr bias = zi ? b1 : b0;
    fptr g    = zi ? g1 : g0;
    fptr be   = zi ? be1 : be0;
    __hip_bfloat16* Z = zi ? Z1 : Z0;
    int n0 = blockIdx.x * 128;
    int r0 = blockIdx.y * 128;
    int t = threadIdx.x, lane = t & 63, w = t >> 6;
    int c = lane & 15, q = lane >> 4;
    int rowbase = (w & 1) * 64, colbase = (w >> 1) * 64;

    f32x4 acc[4][4];
    const f32x4 fzero = {0.f, 0.f, 0.f, 0.f};
    #pragma unroll
    for (int i = 0; i < 4; i++)
        #pragma unroll
        for (int j = 0; j < 4; j++) acc[i][j] = fzero;

    int arow = t >> 1, aseg = t & 1;   // A staging: row, 16-float segment
    int bkk  = t >> 3, bseg = t & 7;   // B staging: k row, 16-float n segment

    for (int k0 = 0; k0 < 1024; k0 += 32) {
        // ---- stage A tile (rows r0.., k k0..k0+31) as bf16 [row][k]
        const float4* ap = (const float4*)(A + (size_t)(r0 + arow) * 1024 + k0 + aseg * 16);
        float4 a0 = ap[0], a1 = ap[1], a2 = ap[2], a3 = ap[3];
        u16x8 p0 = { f2b(a0.x), f2b(a0.y), f2b(a0.z), f2b(a0.w),
                     f2b(a1.x), f2b(a1.y), f2b(a1.z), f2b(a1.w) };
        u16x8 p1 = { f2b(a2.x), f2b(a2.y), f2b(a2.z), f2b(a2.w),
                     f2b(a3.x), f2b(a3.y), f2b(a3.z), f2b(a3.w) };
        *(u16x8*)&As[arow][aseg * 16]     = p0;
        *(u16x8*)&As[arow][aseg * 16 + 8] = p1;
        // ---- stage B tile transposed: Bs[n][k] = W[k0+k][n0+n]
        const float4* bp = (const float4*)(W + (size_t)(k0 + bkk) * 1024 + n0 + bseg * 16);
        float4 w0 = bp[0], w1 = bp[1], w2 = bp[2], w3 = bp[3];
        int nb = bseg * 16;
        Bs[nb +  0][bkk] = f2b(w0.x); Bs[nb +  1][bkk] = f2b(w0.y);
        Bs[nb +  2][bkk] = f2b(w0.z); Bs[nb +  3][bkk] = f2b(w0.w);
        Bs[nb +  4][bkk] = f2b(w1.x); Bs[nb +  5][bkk] = f2b(w1.y);
        Bs[nb +  6][bkk] = f2b(w1.z); Bs[nb +  7][bkk] = f2b(w1.w);
        Bs[nb +  8][bkk] = f2b(w2.x); Bs[nb +  9][bkk] = f2b(w2.y);
        Bs[nb + 10][bkk] = f2b(w2.z); Bs[nb + 11][bkk] = f2b(w2.w);
        Bs[nb + 12][bkk] = f2b(w3.x); Bs[nb + 13][bkk] = f2b(w3.y);
        Bs[nb + 14][bkk] = f2b(w3.z); Bs[nb + 15][bkk] = f2b(w3.w);
        __syncthreads();
        bf16x8 af[4], bfv[4];
        #pragma unroll
        for (int i = 0; i < 4; i++) af[i]  = *(const bf16x8*)&As[rowbase + i * 16 + c][q * 8];
        #pragma unroll
        for (int j = 0; j < 4; j++) bfv[j] = *(const bf16x8*)&Bs[colbase + j * 16 + c][q * 8];
        #pragma unroll
        for (int i = 0; i < 4; i++)
            #pragma unroll
            for (int j = 0; j < 4; j++)
                acc[i][j] = __builtin_amdgcn_mfma_f32_16x16x32_bf16(af[i], bfv[j], acc[i][j], 0, 0, 0);
        __syncthreads();
    }

    // ---- epilogue: bias + elu (in place), per-row stats, groupnorm, bf16 store
    float bcol[4], gcol[4], Bcol[4];
    #pragma unroll
    for (int j = 0; j < 4; j++) {
        int cg = n0 + colbase + j * 16 + c;
        bcol[j] = bias[cg]; gcol[j] = g[cg]; Bcol[j] = be[cg];
    }
    #pragma unroll
    for (int i = 0; i < 4; i++)
        #pragma unroll
        for (int j = 0; j < 4; j++)
            #pragma unroll
            for (int r = 0; r < 4; r++)
                acc[i][j][r] = elu_f(acc[i][j][r] + bcol[j]);
    #pragma unroll
    for (int i = 0; i < 4; i++) {
        #pragma unroll
        for (int r = 0; r < 4; r++) {
            float s  = acc[i][0][r] + acc[i][1][r] + acc[i][2][r] + acc[i][3][r];
            float ss = acc[i][0][r] * acc[i][0][r] + acc[i][1][r] * acc[i][1][r]
                     + acc[i][2][r] * acc[i][2][r] + acc[i][3][r] * acc[i][3][r];
            // reduce over the 16 lanes holding different cols of this row (xor low 4 bits)
            for (int m = 1; m < 16; m <<= 1) { s += __shfl_xor(s, m); ss += __shfl_xor(ss, m); }
            if (c == 0) {
                int rl = rowbase + i * 16 + q * 4 + r;
                sstat[rl][w >> 1][0] = s;
                sstat[rl][w >> 1][1] = ss;
            }
        }
    }
    __syncthreads();
    #pragma unroll
    for (int i = 0; i < 4; i++) {
        #pragma unroll
        for (int r = 0; r < 4; r++) {
            int rl = rowbase + i * 16 + q * 4 + r;
            float S  = sstat[rl][0][0] + sstat[rl][1][0];
            float SS = sstat[rl][0][1] + sstat[rl][1][1];
            float mean = S * (1.f / 128.f);
            float var  = SS * (1.f / 128.f) - mean * mean;
            float inv  = rsqrtf(var + 1e-3f);
            #pragma unroll
            for (int j = 0; j < 4; j++) {
                int cg = n0 + colbase + j * 16 + c;
                float v = (acc[i][j][r] - mean) * inv * gcol[j] + Bcol[j];
                Z[(size_t)(r0 + rl) * 1024 + cg] = __float2bfloat16(v);
            }
        }
    }
}

// ---------------------------------------------------------------------------
// Kernel 3: basic = relu((q*k) @ Wb + bb); pool partials; spatial logits
// grid (mt=16, b=16, h=8), block 256 (4 waves; wave = one m; lane = mid)
// ---------------------------------------------------------------------------
__global__ __launch_bounds__(256) void attn_basic(
    const float* qws, const __hip_bfloat16* kbuf, fptr maskp,
    fptr Wb, fptr bbp, fptr Wl1, fptr bl1,
    float* logits, float* poolpart)
{
    __shared__ float qs[128];
    __shared__ float wb[128 * 64];
    __shared__ float wl1s[64];
    __shared__ float bbs[64];
    __shared__ float poolsh[4][64];
    int mt = blockIdx.x, b = blockIdx.y, h = blockIdx.z;
    int t = threadIdx.x, lane = t & 63, wv = t >> 6;
    if (t < 128) qs[t] = qws[b * 1024 + h * 128 + t];
    for (int i = t; i < 8192; i += 256) wb[i] = Wb[i];
    if (t < 64) { wl1s[t] = Wl1[t]; bbs[t] = bbp[t]; }
    __syncthreads();
    float pool = 0.f;
    float bl1v = bl1[0];
    for (int it = 0; it < 32; it++) {
        int m = mt * 128 + it * 4 + wv;
        const __hip_bfloat16* kr = kbuf + ((size_t)(b * 2048 + m)) * 1024 + h * 128;
        float acc = 0.f;
        #pragma unroll 8
        for (int d = 0; d < 128; d++) {
            acc += qs[d] * BF2F(kr[d]) * wb[d * 64 + lane];
        }
        float basic = fmaxf(acc + bbs[lane], 0.f);
        float mv = maskp[b * 2048 + m];
        pool += basic * mv;
        float lg = basic * wl1s[lane];
        for (int mm = 32; mm > 0; mm >>= 1) lg += __shfl_xor(lg, mm);
        if (lane == 0) logits[(b * 8 + h) * 2048 + m] = lg + bl1v;
    }
    poolsh[wv][lane] = pool;
    __syncthreads();
    if (t < 64) {
        float p = poolsh[0][t] + poolsh[1][t] + poolsh[2][t] + poolsh[3][t];
        poolpart[((b * 8 + h) * 16 + mt) * 64 + t] = p;
    }
}

// ---------------------------------------------------------------------------
// Kernel 4: softmax over M, pool finalize, alpha_ch, v2 aggregation, output
// grid (h=8, b=16), block 256.  fp32 output.
// ---------------------------------------------------------------------------
__global__ __launch_bounds__(256) void finalize(
    const float* logits, const float* poolpart, fptr maskp,
    const __hip_bfloat16* v2buf, const float* v1ws,
    fptr Wl2, fptr bl2, float* out)
{
    __shared__ float alph[2048];
    __shared__ float red[4];
    __shared__ float redm[4];
    __shared__ float pools[64];
    __shared__ float ach[128];
    __shared__ float agg[2][128];
    int h = blockIdx.x, b = blockIdx.y;
    int t = threadIdx.x, lane = t & 63, wv = t >> 6;

    const float* lg = logits + (b * 8 + h) * 2048;
    float msum_l = 0.f, mx_l = -1e30f;
    for (int i = t; i < 2048; i += 256) {
        float mv = maskp[b * 2048 + i];
        msum_l += mv;
        float v = (mv == 0.f) ? -1e9f : lg[i];
        alph[i] = v;
        mx_l = fmaxf(mx_l, v);
    }
    for (int mm = 32; mm > 0; mm >>= 1) {
        msum_l += __shfl_xor(msum_l, mm);
        mx_l = fmaxf(mx_l, __shfl_xor(mx_l, mm));
    }
    if (lane == 0) { red[wv] = msum_l; redm[wv] = mx_l; }
    __syncthreads();
    float msum = red[0] + red[1] + red[2] + red[3];
    float mx = fmaxf(fmaxf(redm[0], redm[1]), fmaxf(redm[2], redm[3]));

    float se = 0.f;
    for (int i = t; i < 2048; i += 256) {
        float e = expf(alph[i] - mx);   // same thread wrote alph[i]
        alph[i] = e;
        se += e;
    }
    for (int mm = 32; mm > 0; mm >>= 1) se += __shfl_xor(se, mm);
    __syncthreads();
    if (lane == 0) red[wv] = se;
    __syncthreads();
    float S = red[0] + red[1] + red[2] + red[3];

    if (t < 64) {
        const float* pp = poolpart + ((size_t)(b * 8 + h) * 16) * 64 + t;
        float p = 0.f;
        for (int pt = 0; pt < 16; pt++) p += pp[pt * 64];
        pools[t] = p / msum;
    }
    __syncthreads();
    if (t < 128) {
        float s2 = bl2[t];
        for (int mid = 0; mid < 64; mid++) s2 += pools[mid] * Wl2[mid * 128 + t];
        ach[t] = 1.f / (1.f + expf(-s2));
    }
    // v2 aggregation: thread t -> d = t&127, m-half = t>>7
    int d = t & 127, half = t >> 7;
    const __hip_bfloat16* v2r = v2buf + ((size_t)(b * 2048 + half * 1024)) * 1024 + h * 128 + d;
    float acc = 0.f;
    for (int mi = 0; mi < 1024; mi++) {
        acc += alph[half * 1024 + mi] * BF2F(v2r[(size_t)mi * 1024]);
    }
    agg[half][d] = acc;
    __syncthreads();
    if (t < 128) {
        float a = (agg[0][t] + agg[1][t]) / S;
        float r = v1ws[b * 1024 + h * 128 + t] * a * ach[t];
        out[b * 1024 + h * 128 + t] = r;
    }
}

// ---------------------------------------------------------------------------
extern "C" void kernel_launch(void* const* d_in, const int* in_sizes, int n_in,
                              void* d_out, int out_size, void* d_ws, size_t ws_size,
                              hipStream_t stream) {
    fptr query  = (fptr)d_in[0];
    fptr key    = (fptr)d_in[1];
    fptr maskp  = (fptr)d_in[2];
    fptr value1 = (fptr)d_in[3];
    fptr value2 = (fptr)d_in[4];
    fptr Wq = (fptr)d_in[5],  bq = (fptr)d_in[6],  gq = (fptr)d_in[7],  Bq = (fptr)d_in[8];
    fptr Wk = (fptr)d_in[9],  bk = (fptr)d_in[10], gk = (fptr)d_in[11], Bk = (fptr)d_in[12];
    fptr Wv1 = (fptr)d_in[13], bv1 = (fptr)d_in[14], gv1 = (fptr)d_in[15], Bv1 = (fptr)d_in[16];
    fptr Wv2 = (fptr)d_in[17], bv2 = (fptr)d_in[18], gv2 = (fptr)d_in[19], Bv2 = (fptr)d_in[20];
    fptr Wb = (fptr)d_in[21], bb = (fptr)d_in[22];
    fptr Wl1 = (fptr)d_in[23], bl1 = (fptr)d_in[24];
    fptr Wl2 = (fptr)d_in[25], bl2 = (fptr)d_in[26];

    char* w = (char*)d_ws;
    __hip_bfloat16* zK  = (__hip_bfloat16*)w;                                   // 64 MB: k (bf16)
    __hip_bfloat16* zV2 = (__hip_bfloat16*)(w + (size_t)64 * 1024 * 1024);      // 64 MB: v2 (bf16)
    float* qws      = (float*)(w + (size_t)128 * 1024 * 1024);                  // 16K f32
    float* v1ws     = qws + 16 * 1024;                                          // 16K f32
    float* logits   = v1ws + 16 * 1024;                                         // 256K f32
    float* poolpart = logits + 16 * 8 * 2048;                                   // 128K f32
    float* out = (float*)d_out;

    hipLaunchKernelGGL(small_proj, dim3(8, 16, 2), dim3(256), 0, stream,
                       query, Wq, bq, gq, Bq, value1, Wv1, bv1, gv1, Bv1, qws, v1ws);
    hipLaunchKernelGGL(mfma_gemm, dim3(8, 256, 2), dim3(256), 0, stream,
                       key, Wk, bk, gk, Bk, value2, Wv2, bv2, gv2, Bv2, zK, zV2);
    hipLaunchKernelGGL(attn_basic, dim3(16, 16, 8), dim3(256), 0, stream,
                       qws, zK, maskp, Wb, bb, Wl1, bl1, logits, poolpart);
    hipLaunchKernelGGL(finalize, dim3(8, 16), dim3(256), 0, stream,
                       logits, poolpart, maskp, zV2, v1ws, Wl2, bl2, out);
}

// Round 3
// 794.311 us; speedup vs baseline: 1.6156x; 1.6156x over previous
//
#include <hip/hip_runtime.h>
#include <hip/hip_bf16.h>
#include <math.h>

typedef __attribute__((ext_vector_type(8))) short bf16x8;     // 8 bf16 = 4 VGPRs
typedef __attribute__((ext_vector_type(4))) float f32x4;      // MFMA accumulator
typedef __attribute__((ext_vector_type(8))) unsigned short u16x8;

typedef const float* fptr;

__device__ inline float b2f(unsigned short u) {
    union { unsigned int i; float f; } v; v.i = ((unsigned int)u) << 16; return v.f;
}
__device__ inline unsigned short f2b(float x) {
    __hip_bfloat16 h = __float2bfloat16(x);
    return *(unsigned short*)&h;
}
#define BF2F(x) __bfloat162float(x)
__device__ inline float elu_f(float x) { return x > 0.f ? x : expm1f(x); }

// async global->LDS, 16 bytes per lane; lds dest = wave-uniform base + lane*16
__device__ inline void load_lds16(const void* g, void* l) {
    __builtin_amdgcn_global_load_lds(
        (const __attribute__((address_space(1))) unsigned int*)g,
        (__attribute__((address_space(3))) unsigned int*)l, 16, 0, 0);
}

// ---------------------------------------------------------------------------
// Kernel 0: transpose+convert W (fp32 [k][n]) -> Wt (bf16 [n][k]).
// grid (16,16,2), block 256, 64x64 tiles via LDS.
// ---------------------------------------------------------------------------
__global__ __launch_bounds__(256) void convert_w(
    fptr W0, fptr W1, unsigned short* Wt0, unsigned short* Wt1)
{
    __shared__ float tl[64][65];
    fptr W = blockIdx.z ? W1 : W0;
    unsigned short* Wt = blockIdx.z ? Wt1 : Wt0;
    int k0 = blockIdx.x * 64, n0 = blockIdx.y * 64;
    int t = threadIdx.x;
    #pragma unroll
    for (int i = 0; i < 16; i++) {
        int kl = i * 4 + (t >> 6), nl = t & 63;
        tl[kl][nl] = W[(size_t)(k0 + kl) * 1024 + n0 + nl];
    }
    __syncthreads();
    #pragma unroll
    for (int i = 0; i < 16; i++) {
        int nl = i * 4 + (t >> 6), kl = t & 63;
        Wt[(size_t)(n0 + nl) * 1024 + k0 + kl] = f2b(tl[kl][nl]);
    }
}

// ---------------------------------------------------------------------------
// Kernel 1: small in_proj (query->q, value1->v1), fp32 in/out (ws)
// ---------------------------------------------------------------------------
__global__ __launch_bounds__(256) void small_proj(
    fptr x0, fptr W0, fptr b0, fptr g0, fptr be0,
    fptr x1, fptr W1, fptr b1, fptr g1, fptr be1,
    float* out0, float* out1)
{
    __shared__ float xs[1024];
    __shared__ float part[2][128];
    __shared__ float r4[4][2];
    int hgrp = blockIdx.x;
    int row  = blockIdx.y;
    int which = blockIdx.z;
    fptr x  = which ? x1  : x0;
    fptr W  = which ? W1  : W0;
    fptr bi = which ? b1  : b0;
    fptr g  = which ? g1  : g0;
    fptr be = which ? be1 : be0;
    float* outp = which ? out1 : out0;
    int t = threadIdx.x, lane = t & 63, wv = t >> 6;
    for (int i = t; i < 1024; i += 256) xs[i] = x[row * 1024 + i];
    __syncthreads();
    int cl = t & 127, kh = t >> 7;
    int col = hgrp * 128 + cl;
    float acc = 0.f;
    const float* wp = W + (size_t)(kh * 512) * 1024 + col;
    for (int k = 0; k < 512; k++) acc += xs[kh * 512 + k] * wp[(size_t)k * 1024];
    part[kh][cl] = acc;
    __syncthreads();
    float e = 0.f;
    if (t < 128) e = elu_f(part[0][t] + part[1][t] + bi[col]);
    float s = e, ss = e * e;
    for (int m = 32; m > 0; m >>= 1) { s += __shfl_xor(s, m); ss += __shfl_xor(ss, m); }
    if (lane == 0) { r4[wv][0] = s; r4[wv][1] = ss; }
    __syncthreads();
    float S  = r4[0][0] + r4[1][0] + r4[2][0] + r4[3][0];
    float SS = r4[0][1] + r4[1][1] + r4[2][1] + r4[3][1];
    float mean = S * (1.f / 128.f);
    float var  = SS * (1.f / 128.f) - mean * mean;
    float inv  = rsqrtf(var + 1e-3f);
    if (t < 128) outp[row * 1024 + col] = (e - mean) * inv * g[col] + be[col];
}

// ---------------------------------------------------------------------------
// Kernel 2: big in_proj via bf16 MFMA (m97-style staging).
// A fp32 -> vector cvt -> ds_write_b128 into As[128][32] bf16 (contiguous).
// B from pre-transposed bf16 Wt via global_load_lds width=16.
// Epilogue: bias+elu+groupnorm fused (verified R2). Z bf16.
// ---------------------------------------------------------------------------
__global__ __launch_bounds__(256) void mfma_gemm(
    fptr A0, const unsigned short* Wt0, fptr b0, fptr g0, fptr be0,
    fptr A1, const unsigned short* Wt1, fptr b1, fptr g1, fptr be1,
    __hip_bfloat16* Z0, __hip_bfloat16* Z1)
{
    __shared__ unsigned short As[128][32];   // [row][k], 64B rows, contiguous
    __shared__ unsigned short Bs[128][32];   // [col][k], via global_load_lds
    __shared__ float sstat[128][2][2];
    int zi = blockIdx.z;
    fptr A    = zi ? A1 : A0;
    const unsigned short* Wt = zi ? Wt1 : Wt0;
    fptr bias = zi ? b1 : b0;
    fptr g    = zi ? g1 : g0;
    fptr be   = zi ? be1 : be0;
    __hip_bfloat16* Z = zi ? Z1 : Z0;
    int n0 = blockIdx.x * 128;
    int r0 = blockIdx.y * 128;
    int t = threadIdx.x, lane = t & 63, w = t >> 6;
    int c = lane & 15, q = lane >> 4;
    int rowbase = (w & 1) * 64, colbase = (w >> 1) * 64;

    f32x4 acc[4][4];
    const f32x4 fzero = {0.f, 0.f, 0.f, 0.f};
    #pragma unroll
    for (int i = 0; i < 4; i++)
        #pragma unroll
        for (int j = 0; j < 4; j++) acc[i][j] = fzero;

    int arow = t >> 1, aseg = (t & 1) * 16;       // A: 2 threads/row, 16 elems each
    int bcol_lo = w * 16 + (lane >> 2);           // B: col within 64-block
    int bko = (lane & 3) * 8;                     // B: k offset (8 bf16 = 16B)

    for (int k0 = 0; k0 < 1024; k0 += 32) {
        // ---- stage B via async global->LDS (2 issues of 64 cols... 2x64)
        load_lds16(Wt + (size_t)(n0 + bcol_lo) * 1024 + k0 + bko,
                   &Bs[w * 16][0]);
        load_lds16(Wt + (size_t)(n0 + 64 + bcol_lo) * 1024 + k0 + bko,
                   &Bs[64 + w * 16][0]);
        // ---- stage A: fp32 load, packed cvt, contiguous ds_write_b128
        const float4* ap = (const float4*)(A + (size_t)(r0 + arow) * 1024 + k0 + aseg);
        float4 a0 = ap[0], a1 = ap[1], a2 = ap[2], a3 = ap[3];
        u16x8 p0 = { f2b(a0.x), f2b(a0.y), f2b(a0.z), f2b(a0.w),
                     f2b(a1.x), f2b(a1.y), f2b(a1.z), f2b(a1.w) };
        u16x8 p1 = { f2b(a2.x), f2b(a2.y), f2b(a2.z), f2b(a2.w),
                     f2b(a3.x), f2b(a3.y), f2b(a3.z), f2b(a3.w) };
        *(u16x8*)&As[arow][aseg]     = p0;
        *(u16x8*)&As[arow][aseg + 8] = p1;
        __syncthreads();
        bf16x8 af[4], bfv[4];
        #pragma unroll
        for (int i = 0; i < 4; i++) af[i]  = *(const bf16x8*)&As[rowbase + i * 16 + c][q * 8];
        #pragma unroll
        for (int j = 0; j < 4; j++) bfv[j] = *(const bf16x8*)&Bs[colbase + j * 16 + c][q * 8];
        #pragma unroll
        for (int i = 0; i < 4; i++)
            #pragma unroll
            for (int j = 0; j < 4; j++)
                acc[i][j] = __builtin_amdgcn_mfma_f32_16x16x32_bf16(af[i], bfv[j], acc[i][j], 0, 0, 0);
        __syncthreads();
    }

    // ---- epilogue: bias + elu, per-row groupnorm (128-col tile == one group)
    float bcol[4], gcol[4], Bcol[4];
    #pragma unroll
    for (int j = 0; j < 4; j++) {
        int cg = n0 + colbase + j * 16 + c;
        bcol[j] = bias[cg]; gcol[j] = g[cg]; Bcol[j] = be[cg];
    }
    #pragma unroll
    for (int i = 0; i < 4; i++)
        #pragma unroll
        for (int j = 0; j < 4; j++)
            #pragma unroll
            for (int r = 0; r < 4; r++)
                acc[i][j][r] = elu_f(acc[i][j][r] + bcol[j]);
    #pragma unroll
    for (int i = 0; i < 4; i++) {
        #pragma unroll
        for (int r = 0; r < 4; r++) {
            float s  = acc[i][0][r] + acc[i][1][r] + acc[i][2][r] + acc[i][3][r];
            float ss = acc[i][0][r] * acc[i][0][r] + acc[i][1][r] * acc[i][1][r]
                     + acc[i][2][r] * acc[i][2][r] + acc[i][3][r] * acc[i][3][r];
            for (int m = 1; m < 16; m <<= 1) { s += __shfl_xor(s, m); ss += __shfl_xor(ss, m); }
            if (c == 0) {
                int rl = rowbase + i * 16 + q * 4 + r;
                sstat[rl][w >> 1][0] = s;
                sstat[rl][w >> 1][1] = ss;
            }
        }
    }
    __syncthreads();
    #pragma unroll
    for (int i = 0; i < 4; i++) {
        #pragma unroll
        for (int r = 0; r < 4; r++) {
            int rl = rowbase + i * 16 + q * 4 + r;
            float S  = sstat[rl][0][0] + sstat[rl][1][0];
            float SS = sstat[rl][0][1] + sstat[rl][1][1];
            float mean = S * (1.f / 128.f);
            float var  = SS * (1.f / 128.f) - mean * mean;
            float inv  = rsqrtf(var + 1e-3f);
            #pragma unroll
            for (int j = 0; j < 4; j++) {
                int cg = n0 + colbase + j * 16 + c;
                float v = (acc[i][j][r] - mean) * inv * gcol[j] + Bcol[j];
                Z[(size_t)(r0 + rl) * 1024 + cg] = __float2bfloat16(v);
            }
        }
    }
}

// ---------------------------------------------------------------------------
// Kernel 3: attn_basic via MFMA.
// A[m][d] = q[d]*k[m][d] (bf16, LDS, padded rows); B = Wb^T [mid][d].
// Outputs: logits[b,h,m] (pre-softmax), poolpart[b,h,mt,mid].
// grid (mt=16, b=16, h=8), block 256 (4 waves; wave w -> m rows w*32..+31).
// ---------------------------------------------------------------------------
__global__ __launch_bounds__(256) void attn_basic(
    const float* qws, const __hip_bfloat16* kbuf, fptr maskp,
    fptr Wb, fptr bbp, fptr Wl1, fptr bl1,
    float* logits, float* poolpart)
{
    __shared__ unsigned short As[128][136];  // [m][d], +16B pad breaks bank cycle
    __shared__ unsigned short Bs[64][136];   // [mid][d]
    __shared__ float qsh[128];
    __shared__ float masksh[128];
    __shared__ float poolred[4][64];
    int mt = blockIdx.x, b = blockIdx.y, h = blockIdx.z;
    int t = threadIdx.x, lane = t & 63, w = t >> 6;
    int c = lane & 15, q = lane >> 4;

    if (t < 128) {
        qsh[t] = qws[b * 1024 + h * 128 + t];
        masksh[t] = maskp[b * 2048 + mt * 128 + t];
    }
    __syncthreads();
    // stage Wb^T: Bs[mid][d] = Wb[d][mid]
    for (int i = 0; i < 32; i++) {
        int idx = i * 256 + t;
        int mid = idx >> 7, d = idx & 127;
        Bs[mid][d] = f2b(Wb[d * 64 + mid]);
    }
    // stage A = q .* k rows (bf16x8 vector loads)
    #pragma unroll
    for (int i = 0; i < 8; i++) {
        int row = i * 16 + (t >> 4);
        int d8 = (t & 15) * 8;
        bf16x8 k8 = *(const bf16x8*)&kbuf[((size_t)(b * 2048 + mt * 128 + row)) * 1024 + h * 128 + d8];
        u16x8 p;
        #pragma unroll
        for (int j = 0; j < 8; j++)
            p[j] = f2b(qsh[d8 + j] * b2f(((unsigned short*)&k8)[j]));
        *(u16x8*)&As[row][d8] = p;
    }
    __syncthreads();

    f32x4 acc[2][4];
    const f32x4 fzero = {0.f, 0.f, 0.f, 0.f};
    #pragma unroll
    for (int i = 0; i < 2; i++)
        #pragma unroll
        for (int j = 0; j < 4; j++) acc[i][j] = fzero;
    #pragma unroll
    for (int s = 0; s < 4; s++) {
        bf16x8 af[2], bfv[4];
        #pragma unroll
        for (int i = 0; i < 2; i++) af[i]  = *(const bf16x8*)&As[w * 32 + i * 16 + c][s * 32 + q * 8];
        #pragma unroll
        for (int j = 0; j < 4; j++) bfv[j] = *(const bf16x8*)&Bs[j * 16 + c][s * 32 + q * 8];
        #pragma unroll
        for (int i = 0; i < 2; i++)
            #pragma unroll
            for (int j = 0; j < 4; j++)
                acc[i][j] = __builtin_amdgcn_mfma_f32_16x16x32_bf16(af[i], bfv[j], acc[i][j], 0, 0, 0);
    }

    // epilogue: relu(acc+bb) -> logits (reduce over mid) + pool (reduce over m)
    float bbs[4], wl1s[4];
    #pragma unroll
    for (int j = 0; j < 4; j++) { bbs[j] = bbp[j * 16 + c]; wl1s[j] = Wl1[j * 16 + c]; }
    float bl1v = bl1[0];
    float pp[4] = {0.f, 0.f, 0.f, 0.f};
    #pragma unroll
    for (int i = 0; i < 2; i++) {
        #pragma unroll
        for (int r = 0; r < 4; r++) {
            int ml = w * 32 + i * 16 + q * 4 + r;
            float mv = masksh[ml];
            float lg = 0.f;
            #pragma unroll
            for (int j = 0; j < 4; j++) {
                float basic = fmaxf(acc[i][j][r] + bbs[j], 0.f);
                lg += basic * wl1s[j];
                pp[j] += basic * mv;
            }
            lg += __shfl_xor(lg, 1); lg += __shfl_xor(lg, 2);
            lg += __shfl_xor(lg, 4); lg += __shfl_xor(lg, 8);
            if (c == 0)
                logits[((size_t)(b * 8 + h)) * 2048 + mt * 128 + ml] = lg + bl1v;
        }
    }
    #pragma unroll
    for (int j = 0; j < 4; j++) {
        pp[j] += __shfl_xor(pp[j], 16);
        pp[j] += __shfl_xor(pp[j], 32);
    }
    if (lane < 16) {
        #pragma unroll
        for (int j = 0; j < 4; j++) poolred[w][j * 16 + c] = pp[j];
    }
    __syncthreads();
    if (t < 64) {
        float p = poolred[0][t] + poolred[1][t] + poolred[2][t] + poolred[3][t];
        poolpart[((size_t)((b * 8 + h) * 16 + mt)) * 64 + t] = p;
    }
}

// ---------------------------------------------------------------------------
// Kernel 4a: softmax (normalized alph -> ws), pool finalize, alpha_ch -> ws
// grid (h=8, b=16), block 256
// ---------------------------------------------------------------------------
__global__ __launch_bounds__(256) void softmax_pool(
    const float* logits, const float* poolpart, fptr maskp,
    fptr Wl2, fptr bl2, float* alphws, float* achws)
{
    __shared__ float alph[2048];
    __shared__ float red[4];
    __shared__ float redm[4];
    __shared__ float pools[64];
    int h = blockIdx.x, b = blockIdx.y;
    int t = threadIdx.x, lane = t & 63, wv = t >> 6;

    const float* lg = logits + (size_t)(b * 8 + h) * 2048;
    float msum_l = 0.f, mx_l = -1e30f;
    for (int i = t; i < 2048; i += 256) {
        float mv = maskp[b * 2048 + i];
        msum_l += mv;
        float v = (mv == 0.f) ? -1e9f : lg[i];
        alph[i] = v;
        mx_l = fmaxf(mx_l, v);
    }
    for (int mm = 32; mm > 0; mm >>= 1) {
        msum_l += __shfl_xor(msum_l, mm);
        mx_l = fmaxf(mx_l, __shfl_xor(mx_l, mm));
    }
    if (lane == 0) { red[wv] = msum_l; redm[wv] = mx_l; }
    __syncthreads();
    float msum = red[0] + red[1] + red[2] + red[3];
    float mx = fmaxf(fmaxf(redm[0], redm[1]), fmaxf(redm[2], redm[3]));

    float se = 0.f;
    for (int i = t; i < 2048; i += 256) {
        float e = expf(alph[i] - mx);
        alph[i] = e;
        se += e;
    }
    for (int mm = 32; mm > 0; mm >>= 1) se += __shfl_xor(se, mm);
    __syncthreads();
    if (lane == 0) red[wv] = se;
    __syncthreads();
    float invS = 1.f / (red[0] + red[1] + red[2] + red[3]);
    for (int i = t; i < 2048; i += 256)
        alphws[(size_t)(b * 8 + h) * 2048 + i] = alph[i] * invS;

    if (t < 64) {
        const float* pq = poolpart + ((size_t)(b * 8 + h) * 16) * 64 + t;
        float p = 0.f;
        for (int pt = 0; pt < 16; pt++) p += pq[pt * 64];
        pools[t] = p / msum;
    }
    __syncthreads();
    if (t < 128) {
        float s2 = bl2[t];
        for (int mid = 0; mid < 64; mid++) s2 += pools[mid] * Wl2[mid * 128 + t];
        achws[(b * 8 + h) * 128 + t] = 1.f / (1.f + expf(-s2));
    }
}

// ---------------------------------------------------------------------------
// Kernel 4b: v2 aggregation partials. grid (seg=4, h=8, b=16), block 256.
// lane: m_off=lane>>4, d8=(lane&15)*8; vectorized bf16x8 v2 reads.
// ---------------------------------------------------------------------------
__global__ __launch_bounds__(256) void v2agg(
    const float* alphws, const __hip_bfloat16* v2buf, float* v2part)
{
    __shared__ float redl[4][128];
    int seg = blockIdx.x, h = blockIdx.y, b = blockIdx.z;
    int t = threadIdx.x, lane = t & 63, wv = t >> 6;
    int mo = lane >> 4, d8 = (lane & 15) * 8;
    const float* al = alphws + (size_t)(b * 8 + h) * 2048;
    float acc[8] = {};
    for (int it = 0; it < 32; it++) {
        int m = seg * 512 + it * 16 + wv * 4 + mo;
        bf16x8 v8 = *(const bf16x8*)&v2buf[((size_t)(b * 2048 + m)) * 1024 + h * 128 + d8];
        float a = al[m];
        #pragma unroll
        for (int j = 0; j < 8; j++)
            acc[j] += a * b2f(((unsigned short*)&v8)[j]);
    }
    #pragma unroll
    for (int j = 0; j < 8; j++) {
        acc[j] += __shfl_xor(acc[j], 16);
        acc[j] += __shfl_xor(acc[j], 32);
    }
    if (lane < 16) {
        #pragma unroll
        for (int j = 0; j < 8; j++) redl[wv][d8 + j] = acc[j];
    }
    __syncthreads();
    if (t < 128) {
        float s = redl[0][t] + redl[1][t] + redl[2][t] + redl[3][t];
        v2part[((size_t)((b * 8 + h) * 4 + seg)) * 128 + t] = s;
    }
}

// ---------------------------------------------------------------------------
// Kernel 4c: combine partials, multiply v1 * agg * ach -> out (fp32)
// grid (16), block 256
// ---------------------------------------------------------------------------
__global__ __launch_bounds__(256) void out_combine(
    const float* v2part, const float* achws, const float* v1ws, float* out)
{
    int b = blockIdx.x, t = threadIdx.x;
    for (int e = t; e < 1024; e += 256) {
        int h = e >> 7, d = e & 127;
        const float* vp = v2part + ((size_t)((b * 8 + h) * 4)) * 128 + d;
        float s = vp[0] + vp[128] + vp[256] + vp[384];
        out[b * 1024 + e] = v1ws[b * 1024 + e] * s * achws[(b * 8 + h) * 128 + d];
    }
}

// ---------------------------------------------------------------------------
extern "C" void kernel_launch(void* const* d_in, const int* in_sizes, int n_in,
                              void* d_out, int out_size, void* d_ws, size_t ws_size,
                              hipStream_t stream) {
    fptr query  = (fptr)d_in[0];
    fptr key    = (fptr)d_in[1];
    fptr maskp  = (fptr)d_in[2];
    fptr value1 = (fptr)d_in[3];
    fptr value2 = (fptr)d_in[4];
    fptr Wq = (fptr)d_in[5],  bq = (fptr)d_in[6],  gq = (fptr)d_in[7],  Bq = (fptr)d_in[8];
    fptr Wk = (fptr)d_in[9],  bk = (fptr)d_in[10], gk = (fptr)d_in[11], Bk = (fptr)d_in[12];
    fptr Wv1 = (fptr)d_in[13], bv1 = (fptr)d_in[14], gv1 = (fptr)d_in[15], Bv1 = (fptr)d_in[16];
    fptr Wv2 = (fptr)d_in[17], bv2 = (fptr)d_in[18], gv2 = (fptr)d_in[19], Bv2 = (fptr)d_in[20];
    fptr Wb = (fptr)d_in[21], bb = (fptr)d_in[22];
    fptr Wl1 = (fptr)d_in[23], bl1 = (fptr)d_in[24];
    fptr Wl2 = (fptr)d_in[25], bl2 = (fptr)d_in[26];

    char* w = (char*)d_ws;
    __hip_bfloat16* zK  = (__hip_bfloat16*)w;                                 // 64 MB
    __hip_bfloat16* zV2 = (__hip_bfloat16*)(w + (size_t)64  * 1024 * 1024);   // 64 MB
    unsigned short* WtK  = (unsigned short*)(w + (size_t)128 * 1024 * 1024);  // 2 MB
    unsigned short* WtV2 = (unsigned short*)(w + (size_t)130 * 1024 * 1024);  // 2 MB
    float* qws      = (float*)(w + (size_t)132 * 1024 * 1024);                // 64 KB
    float* v1ws     = qws + 16 * 1024;                                        // 64 KB
    float* logits   = v1ws + 16 * 1024;                                       // 1 MB
    float* poolpart = logits + 16 * 8 * 2048;                                 // 512 KB
    float* alphws   = poolpart + 16 * 8 * 16 * 64;                            // 1 MB
    float* achws    = alphws + 16 * 8 * 2048;                                 // 64 KB
    float* v2part   = achws + 16 * 8 * 128;                                   // 256 KB
    float* out = (float*)d_out;

    hipLaunchKernelGGL(convert_w, dim3(16, 16, 2), dim3(256), 0, stream,
                       Wk, Wv2, WtK, WtV2);
    hipLaunchKernelGGL(small_proj, dim3(8, 16, 2), dim3(256), 0, stream,
                       query, Wq, bq, gq, Bq, value1, Wv1, bv1, gv1, Bv1, qws, v1ws);
    hipLaunchKernelGGL(mfma_gemm, dim3(8, 256, 2), dim3(256), 0, stream,
                       key, WtK, bk, gk, Bk, value2, WtV2, bv2, gv2, Bv2, zK, zV2);
    hipLaunchKernelGGL(attn_basic, dim3(16, 16, 8), dim3(256), 0, stream,
                       qws, zK, maskp, Wb, bb, Wl1, bl1, logits, poolpart);
    hipLaunchKernelGGL(softmax_pool, dim3(8, 16), dim3(256), 0, stream,
                       logits, poolpart, maskp, Wl2, bl2, alphws, achws);
    hipLaunchKernelGGL(v2agg, dim3(4, 8, 16), dim3(256), 0, stream,
                       alphws, zV2, v2part);
    hipLaunchKernelGGL(out_combine, dim3(16), dim3(256), 0, stream,
                       v2part, achws, v1ws, out);
}

// Round 4
// 689.443 us; speedup vs baseline: 1.8614x; 1.1521x over previous
//
#include <hip/hip_runtime.h>
#include <hip/hip_bf16.h>
#include <math.h>

typedef __attribute__((ext_vector_type(8))) short bf16x8;     // 8 bf16 = 4 VGPRs
typedef __attribute__((ext_vector_type(4))) float f32x4;      // MFMA accumulator
typedef __attribute__((ext_vector_type(8))) unsigned short u16x8;

typedef const float* fptr;
typedef const unsigned short* bfp;

__device__ inline float b2f(unsigned short u) {
    union { unsigned int i; float f; } v; v.i = ((unsigned int)u) << 16; return v.f;
}
__device__ inline unsigned short f2b(float x) {
    __hip_bfloat16 h = __float2bfloat16(x);
    return *(unsigned short*)&h;
}
#define BF2F(x) __bfloat162float(x)
__device__ inline float elu_f(float x) { return x > 0.f ? x : expm1f(x); }

// async global->LDS, 16 bytes per lane; lds dest = wave-uniform base + lane*16
__device__ inline void load_lds16(const void* g, void* l) {
    __builtin_amdgcn_global_load_lds(
        (const __attribute__((address_space(1))) unsigned int*)g,
        (__attribute__((address_space(3))) unsigned int*)l, 16, 0, 0);
}

// ---------------------------------------------------------------------------
// Kernel 0: transpose+convert W (fp32 [k][n]) -> Wt (bf16 [n][k]); z==2 builds
// Wbt (bf16 [mid][d] = Wb^T). grid (16,16,3), block 256.
// ---------------------------------------------------------------------------
__global__ __launch_bounds__(256) void convert_w(
    fptr W0, fptr W1, fptr Wb, unsigned short* Wt0, unsigned short* Wt1,
    unsigned short* Wbt)
{
    __shared__ float tl[64][65];
    __shared__ unsigned short tb[8192];
    int t = threadIdx.x;
    if (blockIdx.z == 2) {
        if (blockIdx.x || blockIdx.y) return;
        for (int i = 0; i < 32; i++) {
            int idx = i * 256 + t;             // idx = d*64 + mid
            tb[(idx & 63) * 128 + (idx >> 6)] = f2b(Wb[idx]);
        }
        __syncthreads();
        for (int i = 0; i < 4; i++) {
            int o = (i * 256 + t) * 8;
            *(u16x8*)&Wbt[o] = *(const u16x8*)&tb[o];
        }
        return;
    }
    fptr W = blockIdx.z ? W1 : W0;
    unsigned short* Wt = blockIdx.z ? Wt1 : Wt0;
    int k0 = blockIdx.x * 64, n0 = blockIdx.y * 64;
    #pragma unroll
    for (int i = 0; i < 16; i++) {
        int kl = i * 4 + (t >> 6), nl = t & 63;
        tl[kl][nl] = W[(size_t)(k0 + kl) * 1024 + n0 + nl];
    }
    __syncthreads();
    #pragma unroll
    for (int i = 0; i < 16; i++) {
        int nl = i * 4 + (t >> 6), kl = t & 63;
        Wt[(size_t)(n0 + nl) * 1024 + k0 + kl] = f2b(tl[kl][nl]);
    }
}

// ---------------------------------------------------------------------------
// Kernel 0b: convert A fp32 -> bf16 contiguous. grid (16384), block 256.
// ---------------------------------------------------------------------------
__global__ __launch_bounds__(256) void convert_a(fptr A, unsigned short* B)
{
    size_t idx = ((size_t)blockIdx.x * 256 + threadIdx.x) * 8;
    const float4* ap = (const float4*)(A + idx);
    float4 a0 = ap[0], a1 = ap[1];
    u16x8 p = { f2b(a0.x), f2b(a0.y), f2b(a0.z), f2b(a0.w),
                f2b(a1.x), f2b(a1.y), f2b(a1.z), f2b(a1.w) };
    *(u16x8*)(B + idx) = p;
}

// ---------------------------------------------------------------------------
// Kernel 1: small in_proj (query->q, value1->v1), fp32 in/out (ws)
// ---------------------------------------------------------------------------
__global__ __launch_bounds__(256) void small_proj(
    fptr x0, fptr W0, fptr b0, fptr g0, fptr be0,
    fptr x1, fptr W1, fptr b1, fptr g1, fptr be1,
    float* out0, float* out1)
{
    __shared__ float xs[1024];
    __shared__ float part[2][128];
    __shared__ float r4[4][2];
    int hgrp = blockIdx.x;
    int row  = blockIdx.y;
    int which = blockIdx.z;
    fptr x  = which ? x1  : x0;
    fptr W  = which ? W1  : W0;
    fptr bi = which ? b1  : b0;
    fptr g  = which ? g1  : g0;
    fptr be = which ? be1 : be0;
    float* outp = which ? out1 : out0;
    int t = threadIdx.x, lane = t & 63, wv = t >> 6;
    for (int i = t; i < 1024; i += 256) xs[i] = x[row * 1024 + i];
    __syncthreads();
    int cl = t & 127, kh = t >> 7;
    int col = hgrp * 128 + cl;
    float acc = 0.f;
    const float* wp = W + (size_t)(kh * 512) * 1024 + col;
    for (int k = 0; k < 512; k++) acc += xs[kh * 512 + k] * wp[(size_t)k * 1024];
    part[kh][cl] = acc;
    __syncthreads();
    float e = 0.f;
    if (t < 128) e = elu_f(part[0][t] + part[1][t] + bi[col]);
    float s = e, ss = e * e;
    for (int m = 32; m > 0; m >>= 1) { s += __shfl_xor(s, m); ss += __shfl_xor(ss, m); }
    if (lane == 0) { r4[wv][0] = s; r4[wv][1] = ss; }
    __syncthreads();
    float S  = r4[0][0] + r4[1][0] + r4[2][0] + r4[3][0];
    float SS = r4[0][1] + r4[1][1] + r4[2][1] + r4[3][1];
    float mean = S * (1.f / 128.f);
    float var  = SS * (1.f / 128.f) - mean * mean;
    float inv  = rsqrtf(var + 1e-3f);
    if (t < 128) outp[row * 1024 + col] = (e - mean) * inv * g[col] + be[col];
}

// ---------------------------------------------------------------------------
// Kernel 2 (fast path): m97-style bf16 GEMM, one matrix per launch.
// A bf16 [r][k], Wt bf16 [n][k]; both staged via global_load_lds width=16.
// 128x128 tile, BK=32, 4 waves (4x4 16x16x32 MFMA each).
// Epilogue: bias + elu + groupnorm fused (verified R2/R3). Z bf16.
// ---------------------------------------------------------------------------
__global__ __launch_bounds__(256) void mfma_gemm_bf(
    bfp A, bfp Wt, fptr bias, fptr g, fptr be, __hip_bfloat16* Z)
{
    __shared__ unsigned short As[128][32];
    __shared__ unsigned short Bs[128][32];
    __shared__ float sstat[128][2][2];
    int n0 = blockIdx.x * 128;
    int r0 = blockIdx.y * 128;
    int t = threadIdx.x, lane = t & 63, w = t >> 6;
    int c = lane & 15, q = lane >> 4;
    int rowbase = (w & 1) * 64, colbase = (w >> 1) * 64;

    f32x4 acc[4][4];
    const f32x4 fzero = {0.f, 0.f, 0.f, 0.f};
    #pragma unroll
    for (int i = 0; i < 4; i++)
        #pragma unroll
        for (int j = 0; j < 4; j++) acc[i][j] = fzero;

    int srow = lane >> 2;            // 0..15 within a 16-row issue
    int sseg = (lane & 3) * 8;       // k offset (8 bf16 = 16 B)
    const unsigned short* ag = A  + (size_t)(r0 + w * 32 + srow) * 1024 + sseg;
    const unsigned short* bg = Wt + (size_t)(n0 + w * 32 + srow) * 1024 + sseg;

    for (int k0 = 0; k0 < 1024; k0 += 32) {
        load_lds16(ag + k0,             &As[w * 32][0]);
        load_lds16(ag + k0 + 16 * 1024, &As[w * 32 + 16][0]);
        load_lds16(bg + k0,             &Bs[w * 32][0]);
        load_lds16(bg + k0 + 16 * 1024, &Bs[w * 32 + 16][0]);
        __syncthreads();
        bf16x8 af[4], bfv[4];
        #pragma unroll
        for (int i = 0; i < 4; i++) af[i]  = *(const bf16x8*)&As[rowbase + i * 16 + c][q * 8];
        #pragma unroll
        for (int j = 0; j < 4; j++) bfv[j] = *(const bf16x8*)&Bs[colbase + j * 16 + c][q * 8];
        #pragma unroll
        for (int i = 0; i < 4; i++)
            #pragma unroll
            for (int j = 0; j < 4; j++)
                acc[i][j] = __builtin_amdgcn_mfma_f32_16x16x32_bf16(af[i], bfv[j], acc[i][j], 0, 0, 0);
        __syncthreads();
    }

    float bcol[4], gcol[4], Bcol[4];
    #pragma unroll
    for (int j = 0; j < 4; j++) {
        int cg = n0 + colbase + j * 16 + c;
        bcol[j] = bias[cg]; gcol[j] = g[cg]; Bcol[j] = be[cg];
    }
    #pragma unroll
    for (int i = 0; i < 4; i++)
        #pragma unroll
        for (int j = 0; j < 4; j++)
            #pragma unroll
            for (int r = 0; r < 4; r++)
                acc[i][j][r] = elu_f(acc[i][j][r] + bcol[j]);
    #pragma unroll
    for (int i = 0; i < 4; i++) {
        #pragma unroll
        for (int r = 0; r < 4; r++) {
            float s  = acc[i][0][r] + acc[i][1][r] + acc[i][2][r] + acc[i][3][r];
            float ss = acc[i][0][r] * acc[i][0][r] + acc[i][1][r] * acc[i][1][r]
                     + acc[i][2][r] * acc[i][2][r] + acc[i][3][r] * acc[i][3][r];
            for (int m = 1; m < 16; m <<= 1) { s += __shfl_xor(s, m); ss += __shfl_xor(ss, m); }
            if (c == 0) {
                int rl = rowbase + i * 16 + q * 4 + r;
                sstat[rl][w >> 1][0] = s;
                sstat[rl][w >> 1][1] = ss;
            }
        }
    }
    __syncthreads();
    #pragma unroll
    for (int i = 0; i < 4; i++) {
        #pragma unroll
        for (int r = 0; r < 4; r++) {
            int rl = rowbase + i * 16 + q * 4 + r;
            float S  = sstat[rl][0][0] + sstat[rl][1][0];
            float SS = sstat[rl][0][1] + sstat[rl][1][1];
            float mean = S * (1.f / 128.f);
            float var  = SS * (1.f / 128.f) - mean * mean;
            float inv  = rsqrtf(var + 1e-3f);
            #pragma unroll
            for (int j = 0; j < 4; j++) {
                int cg = n0 + colbase + j * 16 + c;
                float v = (acc[i][j][r] - mean) * inv * gcol[j] + Bcol[j];
                Z[(size_t)(r0 + rl) * 1024 + cg] = __float2bfloat16(v);
            }
        }
    }
}

// ---------------------------------------------------------------------------
// Kernel 2 (fallback, R3-proven): fp32 A staged with in-kernel cvt.
// ---------------------------------------------------------------------------
__global__ __launch_bounds__(256) void mfma_gemm_f32(
    fptr A0, bfp Wt0, fptr b0, fptr g0, fptr be0,
    fptr A1, bfp Wt1, fptr b1, fptr g1, fptr be1,
    __hip_bfloat16* Z0, __hip_bfloat16* Z1)
{
    __shared__ unsigned short As[128][32];
    __shared__ unsigned short Bs[128][32];
    __shared__ float sstat[128][2][2];
    int zi = blockIdx.z;
    fptr A    = zi ? A1 : A0;
    bfp Wt    = zi ? Wt1 : Wt0;
    fptr bias = zi ? b1 : b0;
    fptr g    = zi ? g1 : g0;
    fptr be   = zi ? be1 : be0;
    __hip_bfloat16* Z = zi ? Z1 : Z0;
    int n0 = blockIdx.x * 128;
    int r0 = blockIdx.y * 128;
    int t = threadIdx.x, lane = t & 63, w = t >> 6;
    int c = lane & 15, q = lane >> 4;
    int rowbase = (w & 1) * 64, colbase = (w >> 1) * 64;

    f32x4 acc[4][4];
    const f32x4 fzero = {0.f, 0.f, 0.f, 0.f};
    #pragma unroll
    for (int i = 0; i < 4; i++)
        #pragma unroll
        for (int j = 0; j < 4; j++) acc[i][j] = fzero;

    int arow = t >> 1, aseg = (t & 1) * 16;
    int srow = lane >> 2, sseg = (lane & 3) * 8;
    const unsigned short* bg = Wt + (size_t)(n0 + w * 32 + srow) * 1024 + sseg;

    for (int k0 = 0; k0 < 1024; k0 += 32) {
        load_lds16(bg + k0,             &Bs[w * 32][0]);
        load_lds16(bg + k0 + 16 * 1024, &Bs[w * 32 + 16][0]);
        const float4* ap = (const float4*)(A + (size_t)(r0 + arow) * 1024 + k0 + aseg);
        float4 a0 = ap[0], a1 = ap[1], a2 = ap[2], a3 = ap[3];
        u16x8 p0 = { f2b(a0.x), f2b(a0.y), f2b(a0.z), f2b(a0.w),
                     f2b(a1.x), f2b(a1.y), f2b(a1.z), f2b(a1.w) };
        u16x8 p1 = { f2b(a2.x), f2b(a2.y), f2b(a2.z), f2b(a2.w),
                     f2b(a3.x), f2b(a3.y), f2b(a3.z), f2b(a3.w) };
        *(u16x8*)&As[arow][aseg]     = p0;
        *(u16x8*)&As[arow][aseg + 8] = p1;
        __syncthreads();
        bf16x8 af[4], bfv[4];
        #pragma unroll
        for (int i = 0; i < 4; i++) af[i]  = *(const bf16x8*)&As[rowbase + i * 16 + c][q * 8];
        #pragma unroll
        for (int j = 0; j < 4; j++) bfv[j] = *(const bf16x8*)&Bs[colbase + j * 16 + c][q * 8];
        #pragma unroll
        for (int i = 0; i < 4; i++)
            #pragma unroll
            for (int j = 0; j < 4; j++)
                acc[i][j] = __builtin_amdgcn_mfma_f32_16x16x32_bf16(af[i], bfv[j], acc[i][j], 0, 0, 0);
        __syncthreads();
    }

    float bcol[4], gcol[4], Bcol[4];
    #pragma unroll
    for (int j = 0; j < 4; j++) {
        int cg = n0 + colbase + j * 16 + c;
        bcol[j] = bias[cg]; gcol[j] = g[cg]; Bcol[j] = be[cg];
    }
    #pragma unroll
    for (int i = 0; i < 4; i++)
        #pragma unroll
        for (int j = 0; j < 4; j++)
            #pragma unroll
            for (int r = 0; r < 4; r++)
                acc[i][j][r] = elu_f(acc[i][j][r] + bcol[j]);
    #pragma unroll
    for (int i = 0; i < 4; i++) {
        #pragma unroll
        for (int r = 0; r < 4; r++) {
            float s  = acc[i][0][r] + acc[i][1][r] + acc[i][2][r] + acc[i][3][r];
            float ss = acc[i][0][r] * acc[i][0][r] + acc[i][1][r] * acc[i][1][r]
                     + acc[i][2][r] * acc[i][2][r] + acc[i][3][r] * acc[i][3][r];
            for (int m = 1; m < 16; m <<= 1) { s += __shfl_xor(s, m); ss += __shfl_xor(ss, m); }
            if (c == 0) {
                int rl = rowbase + i * 16 + q * 4 + r;
                sstat[rl][w >> 1][0] = s;
                sstat[rl][w >> 1][1] = ss;
            }
        }
    }
    __syncthreads();
    #pragma unroll
    for (int i = 0; i < 4; i++) {
        #pragma unroll
        for (int r = 0; r < 4; r++) {
            int rl = rowbase + i * 16 + q * 4 + r;
            float S  = sstat[rl][0][0] + sstat[rl][1][0];
            float SS = sstat[rl][0][1] + sstat[rl][1][1];
            float mean = S * (1.f / 128.f);
            float var  = SS * (1.f / 128.f) - mean * mean;
            float inv  = rsqrtf(var + 1e-3f);
            #pragma unroll
            for (int j = 0; j < 4; j++) {
                int cg = n0 + colbase + j * 16 + c;
                float v = (acc[i][j][r] - mean) * inv * gcol[j] + Bcol[j];
                Z[(size_t)(r0 + rl) * 1024 + cg] = __float2bfloat16(v);
            }
        }
    }
}

// ---------------------------------------------------------------------------
// Kernel 3: attn_basic via MFMA. A[m][d] = q[d]*k[m][d] (bf16 LDS, padded);
// B = Wbt [mid][d] (pre-transposed bf16). grid (mt=16, b=16, h=8), block 256.
// ---------------------------------------------------------------------------
__global__ __launch_bounds__(256) void attn_basic(
    const float* qws, const __hip_bfloat16* kbuf, fptr maskp,
    bfp Wbt, fptr bbp, fptr Wl1, fptr bl1,
    float* logits, float* poolpart)
{
    __shared__ unsigned short As[128][136];
    __shared__ unsigned short Bs[64][136];
    __shared__ float qsh[128];
    __shared__ float masksh[128];
    __shared__ float poolred[4][64];
    int mt = blockIdx.x, b = blockIdx.y, h = blockIdx.z;
    int t = threadIdx.x, lane = t & 63, w = t >> 6;
    int c = lane & 15, q = lane >> 4;

    if (t < 128) {
        qsh[t] = qws[b * 1024 + h * 128 + t];
        masksh[t] = maskp[b * 2048 + mt * 128 + t];
    }
    __syncthreads();
    // stage Wbt (bf16 [mid][d]) with vector loads
    #pragma unroll
    for (int i = 0; i < 4; i++) {
        int idx = i * 256 + t;
        int mid = idx >> 4, d8 = (idx & 15) * 8;
        *(u16x8*)&Bs[mid][d8] = *(const u16x8*)&Wbt[mid * 128 + d8];
    }
    // stage A = q .* k rows (bf16x8 vector loads)
    #pragma unroll
    for (int i = 0; i < 8; i++) {
        int row = i * 16 + (t >> 4);
        int d8 = (t & 15) * 8;
        bf16x8 k8 = *(const bf16x8*)&kbuf[((size_t)(b * 2048 + mt * 128 + row)) * 1024 + h * 128 + d8];
        u16x8 p;
        #pragma unroll
        for (int j = 0; j < 8; j++)
            p[j] = f2b(qsh[d8 + j] * b2f(((unsigned short*)&k8)[j]));
        *(u16x8*)&As[row][d8] = p;
    }
    __syncthreads();

    f32x4 acc[2][4];
    const f32x4 fzero = {0.f, 0.f, 0.f, 0.f};
    #pragma unroll
    for (int i = 0; i < 2; i++)
        #pragma unroll
        for (int j = 0; j < 4; j++) acc[i][j] = fzero;
    #pragma unroll
    for (int s = 0; s < 4; s++) {
        bf16x8 af[2], bfv[4];
        #pragma unroll
        for (int i = 0; i < 2; i++) af[i]  = *(const bf16x8*)&As[w * 32 + i * 16 + c][s * 32 + q * 8];
        #pragma unroll
        for (int j = 0; j < 4; j++) bfv[j] = *(const bf16x8*)&Bs[j * 16 + c][s * 32 + q * 8];
        #pragma unroll
        for (int i = 0; i < 2; i++)
            #pragma unroll
            for (int j = 0; j < 4; j++)
                acc[i][j] = __builtin_amdgcn_mfma_f32_16x16x32_bf16(af[i], bfv[j], acc[i][j], 0, 0, 0);
    }

    float bbs[4], wl1s[4];
    #pragma unroll
    for (int j = 0; j < 4; j++) { bbs[j] = bbp[j * 16 + c]; wl1s[j] = Wl1[j * 16 + c]; }
    float bl1v = bl1[0];
    float pp[4] = {0.f, 0.f, 0.f, 0.f};
    #pragma unroll
    for (int i = 0; i < 2; i++) {
        #pragma unroll
        for (int r = 0; r < 4; r++) {
            int ml = w * 32 + i * 16 + q * 4 + r;
            float mv = masksh[ml];
            float lg = 0.f;
            #pragma unroll
            for (int j = 0; j < 4; j++) {
                float basic = fmaxf(acc[i][j][r] + bbs[j], 0.f);
                lg += basic * wl1s[j];
                pp[j] += basic * mv;
            }
            lg += __shfl_xor(lg, 1); lg += __shfl_xor(lg, 2);
            lg += __shfl_xor(lg, 4); lg += __shfl_xor(lg, 8);
            if (c == 0)
                logits[((size_t)(b * 8 + h)) * 2048 + mt * 128 + ml] = lg + bl1v;
        }
    }
    #pragma unroll
    for (int j = 0; j < 4; j++) {
        pp[j] += __shfl_xor(pp[j], 16);
        pp[j] += __shfl_xor(pp[j], 32);
    }
    if (lane < 16) {
        #pragma unroll
        for (int j = 0; j < 4; j++) poolred[w][j * 16 + c] = pp[j];
    }
    __syncthreads();
    if (t < 64) {
        float p = poolred[0][t] + poolred[1][t] + poolred[2][t] + poolred[3][t];
        poolpart[((size_t)((b * 8 + h) * 16 + mt)) * 64 + t] = p;
    }
}

// ---------------------------------------------------------------------------
// Kernel 4a: softmax -> normalized alph (ws), pool finalize, alpha_ch (ws)
// ---------------------------------------------------------------------------
__global__ __launch_bounds__(256) void softmax_pool(
    const float* logits, const float* poolpart, fptr maskp,
    fptr Wl2, fptr bl2, float* alphws, float* achws)
{
    __shared__ float alph[2048];
    __shared__ float red[4];
    __shared__ float redm[4];
    __shared__ float pools[64];
    int h = blockIdx.x, b = blockIdx.y;
    int t = threadIdx.x, lane = t & 63, wv = t >> 6;

    const float* lg = logits + (size_t)(b * 8 + h) * 2048;
    float msum_l = 0.f, mx_l = -1e30f;
    for (int i = t; i < 2048; i += 256) {
        float mv = maskp[b * 2048 + i];
        msum_l += mv;
        float v = (mv == 0.f) ? -1e9f : lg[i];
        alph[i] = v;
        mx_l = fmaxf(mx_l, v);
    }
    for (int mm = 32; mm > 0; mm >>= 1) {
        msum_l += __shfl_xor(msum_l, mm);
        mx_l = fmaxf(mx_l, __shfl_xor(mx_l, mm));
    }
    if (lane == 0) { red[wv] = msum_l; redm[wv] = mx_l; }
    __syncthreads();
    float msum = red[0] + red[1] + red[2] + red[3];
    float mx = fmaxf(fmaxf(redm[0], redm[1]), fmaxf(redm[2], redm[3]));

    float se = 0.f;
    for (int i = t; i < 2048; i += 256) {
        float e = expf(alph[i] - mx);
        alph[i] = e;
        se += e;
    }
    for (int mm = 32; mm > 0; mm >>= 1) se += __shfl_xor(se, mm);
    __syncthreads();
    if (lane == 0) red[wv] = se;
    __syncthreads();
    float invS = 1.f / (red[0] + red[1] + red[2] + red[3]);
    for (int i = t; i < 2048; i += 256)
        alphws[(size_t)(b * 8 + h) * 2048 + i] = alph[i] * invS;

    if (t < 64) {
        const float* pq = poolpart + ((size_t)(b * 8 + h) * 16) * 64 + t;
        float p = 0.f;
        for (int pt = 0; pt < 16; pt++) p += pq[pt * 64];
        pools[t] = p / msum;
    }
    __syncthreads();
    if (t < 128) {
        float s2 = bl2[t];
        for (int mid = 0; mid < 64; mid++) s2 += pools[mid] * Wl2[mid * 128 + t];
        achws[(b * 8 + h) * 128 + t] = 1.f / (1.f + expf(-s2));
    }
}

// ---------------------------------------------------------------------------
// Kernel 4b: v2 aggregation partials. grid (seg=4, h=8, b=16), block 256.
// ---------------------------------------------------------------------------
__global__ __launch_bounds__(256) void v2agg(
    const float* alphws, const __hip_bfloat16* v2buf, float* v2part)
{
    __shared__ float redl[4][128];
    int seg = blockIdx.x, h = blockIdx.y, b = blockIdx.z;
    int t = threadIdx.x, lane = t & 63, wv = t >> 6;
    int mo = lane >> 4, d8 = (lane & 15) * 8;
    const float* al = alphws + (size_t)(b * 8 + h) * 2048;
    float acc[8] = {};
    for (int it = 0; it < 32; it++) {
        int m = seg * 512 + it * 16 + wv * 4 + mo;
        bf16x8 v8 = *(const bf16x8*)&v2buf[((size_t)(b * 2048 + m)) * 1024 + h * 128 + d8];
        float a = al[m];
        #pragma unroll
        for (int j = 0; j < 8; j++)
            acc[j] += a * b2f(((unsigned short*)&v8)[j]);
    }
    #pragma unroll
    for (int j = 0; j < 8; j++) {
        acc[j] += __shfl_xor(acc[j], 16);
        acc[j] += __shfl_xor(acc[j], 32);
    }
    if (lane < 16) {
        #pragma unroll
        for (int j = 0; j < 8; j++) redl[wv][d8 + j] = acc[j];
    }
    __syncthreads();
    if (t < 128) {
        float s = redl[0][t] + redl[1][t] + redl[2][t] + redl[3][t];
        v2part[((size_t)((b * 8 + h) * 4 + seg)) * 128 + t] = s;
    }
}

// ---------------------------------------------------------------------------
// Kernel 4c: combine partials, out = v1 * agg * ach (fp32). grid (16).
// ---------------------------------------------------------------------------
__global__ __launch_bounds__(256) void out_combine(
    const float* v2part, const float* achws, const float* v1ws, float* out)
{
    int b = blockIdx.x, t = threadIdx.x;
    for (int e = t; e < 1024; e += 256) {
        int h = e >> 7, d = e & 127;
        const float* vp = v2part + ((size_t)((b * 8 + h) * 4)) * 128 + d;
        float s = vp[0] + vp[128] + vp[256] + vp[384];
        out[b * 1024 + e] = v1ws[b * 1024 + e] * s * achws[(b * 8 + h) * 128 + d];
    }
}

// ---------------------------------------------------------------------------
extern "C" void kernel_launch(void* const* d_in, const int* in_sizes, int n_in,
                              void* d_out, int out_size, void* d_ws, size_t ws_size,
                              hipStream_t stream) {
    fptr query  = (fptr)d_in[0];
    fptr key    = (fptr)d_in[1];
    fptr maskp  = (fptr)d_in[2];
    fptr value1 = (fptr)d_in[3];
    fptr value2 = (fptr)d_in[4];
    fptr Wq = (fptr)d_in[5],  bq = (fptr)d_in[6],  gq = (fptr)d_in[7],  Bq = (fptr)d_in[8];
    fptr Wk = (fptr)d_in[9],  bk = (fptr)d_in[10], gk = (fptr)d_in[11], Bk = (fptr)d_in[12];
    fptr Wv1 = (fptr)d_in[13], bv1 = (fptr)d_in[14], gv1 = (fptr)d_in[15], Bv1 = (fptr)d_in[16];
    fptr Wv2 = (fptr)d_in[17], bv2 = (fptr)d_in[18], gv2 = (fptr)d_in[19], Bv2 = (fptr)d_in[20];
    fptr Wb = (fptr)d_in[21], bb = (fptr)d_in[22];
    fptr Wl1 = (fptr)d_in[23], bl1 = (fptr)d_in[24];
    fptr Wl2 = (fptr)d_in[25], bl2 = (fptr)d_in[26];

    const size_t MB = 1024 * 1024;
    char* w = (char*)d_ws;
    __hip_bfloat16* zK  = (__hip_bfloat16*)w;                        // 64 MB
    __hip_bfloat16* zV2 = (__hip_bfloat16*)(w + 64 * MB);            // 64 MB
    unsigned short* WtK  = (unsigned short*)(w + 128 * MB);          // 2 MB
    unsigned short* WtV2 = (unsigned short*)(w + 130 * MB);          // 2 MB
    unsigned short* Wbt  = (unsigned short*)(w + 132 * MB);          // 16 KB
    float* qws      = (float*)(w + 132 * MB + 65536);                // 64 KB
    float* v1ws     = qws + 16 * 1024;                               // 64 KB
    float* logits   = v1ws + 16 * 1024;                              // 1 MB
    float* poolpart = logits + 16 * 8 * 2048;                        // 512 KB
    float* alphws   = poolpart + 16 * 8 * 16 * 64;                   // 1 MB
    float* achws    = alphws + 16 * 8 * 2048;                        // 64 KB
    float* v2part   = achws + 16 * 8 * 128;                          // 256 KB
    unsigned short* Abf = (unsigned short*)(w + 136 * MB);           // 64 MB (fast path)
    float* out = (float*)d_out;

    bool fast = ws_size >= 200 * MB;

    hipLaunchKernelGGL(convert_w, dim3(16, 16, 3), dim3(256), 0, stream,
                       Wk, Wv2, Wb, WtK, WtV2, Wbt);
    hipLaunchKernelGGL(small_proj, dim3(8, 16, 2), dim3(256), 0, stream,
                       query, Wq, bq, gq, Bq, value1, Wv1, bv1, gv1, Bv1, qws, v1ws);
    if (fast) {
        hipLaunchKernelGGL(convert_a, dim3(16384), dim3(256), 0, stream, key, Abf);
        hipLaunchKernelGGL(mfma_gemm_bf, dim3(8, 256), dim3(256), 0, stream,
                           (bfp)Abf, (bfp)WtK, bk, gk, Bk, zK);
        hipLaunchKernelGGL(convert_a, dim3(16384), dim3(256), 0, stream, value2, Abf);
        hipLaunchKernelGGL(mfma_gemm_bf, dim3(8, 256), dim3(256), 0, stream,
                           (bfp)Abf, (bfp)WtV2, bv2, gv2, Bv2, zV2);
    } else {
        hipLaunchKernelGGL(mfma_gemm_f32, dim3(8, 256, 2), dim3(256), 0, stream,
                           key, (bfp)WtK, bk, gk, Bk, value2, (bfp)WtV2, bv2, gv2, Bv2, zK, zV2);
    }
    hipLaunchKernelGGL(attn_basic, dim3(16, 16, 8), dim3(256), 0, stream,
                       qws, zK, maskp, (bfp)Wbt, bb, Wl1, bl1, logits, poolpart);
    hipLaunchKernelGGL(softmax_pool, dim3(8, 16), dim3(256), 0, stream,
                       logits, poolpart, maskp, Wl2, bl2, alphws, achws);
    hipLaunchKernelGGL(v2agg, dim3(4, 8, 16), dim3(256), 0, stream,
                       alphws, zV2, v2part);
    hipLaunchKernelGGL(out_combine, dim3(16), dim3(256), 0, stream,
                       v2part, achws, v1ws, out);
}